// Round 2
// baseline (766.742 us; speedup 1.0000x reference)
//
#include <hip/hip_runtime.h>
#include <hip/hip_bf16.h>

// ChebConv, K=4: out[b,v,o] = bias[o] + sum_{c<256} xs[c&3][v,(c>>2)*2+b] * Wflat[c*64+o]
// xs: x0[v,f*2+b]=inputs[b,v,f]; x1 = L x0; x_k = 2 L x_{k-1} - x_{k-2}.
// L applied via per-call CSR build (hist -> scan -> scatter), atomic-free pull spmm.
// All float tensors are float32 (reference dtype).

#define NV 50000
#define NE 800000
#define NB 2
#define NFIN 64
#define NFOUT 64
#define NC 128  // NFIN*NB

__global__ void zero_cnt_k(int* __restrict__ cnt) {
    int i = blockIdx.x * blockDim.x + threadIdx.x;
    if (i < NV) cnt[i] = 0;
}

__global__ void hist_k(const int* __restrict__ rows, int* __restrict__ cnt) {
    int i = blockIdx.x * blockDim.x + threadIdx.x;
    if (i < NE) atomicAdd(&cnt[rows[i]], 1);
}

__global__ __launch_bounds__(1024) void scan_k(const int* __restrict__ cnt,
                                               int* __restrict__ row_ptr,
                                               int* __restrict__ row_fill) {
    __shared__ int sums[1024];
    int t = threadIdx.x;
    const int per = (NV + 1023) / 1024;  // 49
    int base = t * per;
    int local = 0;
    for (int i = 0; i < per; ++i) {
        int idx = base + i;
        if (idx < NV) local += cnt[idx];
    }
    sums[t] = local;
    __syncthreads();
    for (int off = 1; off < 1024; off <<= 1) {
        int v = (t >= off) ? sums[t - off] : 0;
        __syncthreads();
        sums[t] += v;
        __syncthreads();
    }
    int run = (t == 0) ? 0 : sums[t - 1];
    for (int i = 0; i < per; ++i) {
        int idx = base + i;
        if (idx < NV) {
            row_ptr[idx] = run;
            row_fill[idx] = run;
            run += cnt[idx];
        }
    }
    if (t == 1023) row_ptr[NV] = sums[1023];  // == NE
}

__global__ void scatter_k(const int* __restrict__ rows, const int* __restrict__ cols,
                          const float* __restrict__ vals,
                          int* __restrict__ row_fill,
                          float* __restrict__ sval, int* __restrict__ scol) {
    int i = blockIdx.x * blockDim.x + threadIdx.x;
    if (i < NE) {
        int r = rows[i];
        int p = atomicAdd(&row_fill[r], 1);
        sval[p] = vals[i];
        scol[p] = cols[i];
    }
}

// x0[v, f*2+b] = inputs[b, v, f]; thread per (v,f), writes float2 (b=0,1)
__global__ void build_x0_k(const float* __restrict__ in, float* __restrict__ x0) {
    int i = blockIdx.x * blockDim.x + threadIdx.x;  // v*64 + f
    if (i < NV * NFIN) {
        float a = in[i];                          // b=0
        float b = in[(size_t)NV * NFIN + i];      // b=1
        int v = i >> 6, f = i & 63;
        float2* o = (float2*)(x0 + (size_t)v * NC + f * 2);
        *o = make_float2(a, b);
    }
}

// One wave per row. mode 0: xout = L x ; mode 1: xout = 2 L x - xprev
__global__ __launch_bounds__(256) void spmm_k(const float* __restrict__ x,
                                              const float* __restrict__ xprev,
                                              const int* __restrict__ row_ptr,
                                              const int* __restrict__ scol,
                                              const float* __restrict__ sval,
                                              float* __restrict__ xout, int mode) {
    int wave = (blockIdx.x * blockDim.x + threadIdx.x) >> 6;
    int lane = threadIdx.x & 63;
    if (wave >= NV) return;
    int beg = row_ptr[wave];
    int end = row_ptr[wave + 1];
    float accx = 0.f, accy = 0.f;
    for (int e = beg; e < end; ++e) {
        int c = scol[e];
        float val = sval[e];
        float2 xv = ((const float2*)(x + (size_t)c * NC))[lane];
        accx += val * xv.x;
        accy += val * xv.y;
    }
    float2 res;
    if (mode) {
        float2 pv = ((const float2*)(xprev + (size_t)wave * NC))[lane];
        res.x = 2.f * accx - pv.x;
        res.y = 2.f * accy - pv.y;
    } else {
        res.x = accx;
        res.y = accy;
    }
    ((float2*)(xout + (size_t)wave * NC))[lane] = res;
}

// One wave per v (grid-stride); lane = o. Weight (fp32, 64KB) staged in LDS.
__global__ __launch_bounds__(512) void final_k(const float* __restrict__ x0,
                                               const float* __restrict__ x1,
                                               const float* __restrict__ x2,
                                               const float* __restrict__ x3,
                                               const float* __restrict__ weight,
                                               const float* __restrict__ bias,
                                               float* __restrict__ out) {
    __shared__ float wlds[256 * 64];  // Wflat[c][o], 64 KB
    for (int i = threadIdx.x; i < 256 * 64; i += 512) {
        wlds[i] = weight[i];
    }
    __syncthreads();

    int lane = threadIdx.x & 63;  // = o
    int wid = threadIdx.x >> 6;   // 0..7
    int wgv = blockIdx.x * 8 + wid;
    int stride = gridDim.x * 8;
    float bv = bias[lane];

    for (int v = wgv; v < NV; v += stride) {
        size_t off = (size_t)v * NC;
        float acc0 = 0.f, acc1 = 0.f;
        #pragma unroll 4
        for (int f = 0; f < 64; ++f) {
            float2 a0 = *(const float2*)(x0 + off + 2 * f);
            float2 a1 = *(const float2*)(x1 + off + 2 * f);
            float2 a2 = *(const float2*)(x2 + off + 2 * f);
            float2 a3 = *(const float2*)(x3 + off + 2 * f);
            float w0 = wlds[(f * 4 + 0) * 64 + lane];
            float w1 = wlds[(f * 4 + 1) * 64 + lane];
            float w2 = wlds[(f * 4 + 2) * 64 + lane];
            float w3 = wlds[(f * 4 + 3) * 64 + lane];
            acc0 += a0.x * w0 + a1.x * w1 + a2.x * w2 + a3.x * w3;
            acc1 += a0.y * w0 + a1.y * w1 + a2.y * w2 + a3.y * w3;
        }
        out[(size_t)v * NFOUT + lane] = acc0 + bv;                          // b=0
        out[(size_t)NV * NFOUT + (size_t)v * NFOUT + lane] = acc1 + bv;     // b=1
    }
}

extern "C" void kernel_launch(void* const* d_in, const int* in_sizes, int n_in,
                              void* d_out, int out_size, void* d_ws, size_t ws_size,
                              hipStream_t stream) {
    const float* inputs = (const float*)d_in[0];  // [B,V,FIN]
    const float* weight = (const float*)d_in[1];  // [K,FIN,FOUT]
    const float* bias   = (const float*)d_in[2];  // [FOUT]
    const float* lapv   = (const float*)d_in[3];  // [E]
    const int*   lrows  = (const int*)d_in[4];    // [E]
    const int*   lcols  = (const int*)d_in[5];    // [E]
    float* out = (float*)d_out;                   // [B,V,FOUT]

    char* ws = (char*)d_ws;
    size_t o = 0;
    auto alloc = [&](size_t bytes) -> void* {
        void* p = ws + o;
        o += (bytes + 255) & ~(size_t)255;
        return p;
    };
    float* x0 = (float*)alloc((size_t)NV * NC * 4);
    float* x1 = (float*)alloc((size_t)NV * NC * 4);
    float* x2 = (float*)alloc((size_t)NV * NC * 4);
    float* x3 = (float*)alloc((size_t)NV * NC * 4);
    float* sval = (float*)alloc((size_t)NE * 4);
    int* scol = (int*)alloc((size_t)NE * 4);
    int* row_ptr = (int*)alloc((size_t)(NV + 1) * 4);
    int* row_fill = (int*)alloc((size_t)(NV + 1) * 4);
    int* cnt = (int*)alloc((size_t)NV * 4);
    (void)ws_size; (void)in_sizes; (void)n_in; (void)out_size;

    zero_cnt_k<<<(NV + 255) / 256, 256, 0, stream>>>(cnt);
    hist_k<<<(NE + 255) / 256, 256, 0, stream>>>(lrows, cnt);
    scan_k<<<1, 1024, 0, stream>>>(cnt, row_ptr, row_fill);
    scatter_k<<<(NE + 255) / 256, 256, 0, stream>>>(lrows, lcols, lapv, row_fill, sval, scol);
    build_x0_k<<<(NV * NFIN + 255) / 256, 256, 0, stream>>>(inputs, x0);

    spmm_k<<<NV / 4, 256, 0, stream>>>(x0, nullptr, row_ptr, scol, sval, x1, 0);
    spmm_k<<<NV / 4, 256, 0, stream>>>(x1, x0, row_ptr, scol, sval, x2, 1);
    spmm_k<<<NV / 4, 256, 0, stream>>>(x2, x1, row_ptr, scol, sval, x3, 1);

    final_k<<<512, 512, 0, stream>>>(x0, x1, x2, x3, weight, bias, out);
}

// Round 3
// 473.421 us; speedup vs baseline: 1.6196x; 1.6196x over previous
//
#include <hip/hip_runtime.h>
#include <hip/hip_bf16.h>

// ChebConv K=4. out[b,v,o] = bias[o] + sum_{c<256} xs[c&3][v,(c>>2)*2+b] * Wflat[c*64+o]
// xs interleaved over batch: x[v, f*2+b]. CSR build -> pull spmm (unroll-8 MLP) ->
// scalar-weight GEMM epilogue (lane=(v,b) row, W via s_load broadcast).

#define NV 50000
#define NE 800000
#define NC 128        // 64 features * 2 batches, interleaved
#define NROWS 100000  // (v,b) rows in the final GEMM
#define SCAN_NBLK 196 // ceil(NV/256)

__global__ void zero_cnt_k(int* __restrict__ cnt) {
    int i = blockIdx.x * blockDim.x + threadIdx.x;
    if (i < NV) cnt[i] = 0;
}

__global__ void hist_k(const int* __restrict__ rows, int* __restrict__ cnt) {
    int i = blockIdx.x * blockDim.x + threadIdx.x;
    if (i < NE) atomicAdd(&cnt[rows[i]], 1);
}

// three-phase exclusive scan of cnt[NV] -> row_ptr / row_fill
__global__ __launch_bounds__(256) void scan1_k(const int* __restrict__ cnt, int* __restrict__ bsum) {
    __shared__ int s[256];
    int t = threadIdx.x;
    int i = blockIdx.x * 256 + t;
    s[t] = (i < NV) ? cnt[i] : 0;
    __syncthreads();
    for (int off = 128; off > 0; off >>= 1) {
        if (t < off) s[t] += s[t + off];
        __syncthreads();
    }
    if (t == 0) bsum[blockIdx.x] = s[0];
}

__global__ __launch_bounds__(256) void scan2_k(int* __restrict__ bsum) {
    __shared__ int s[256];
    int t = threadIdx.x;
    s[t] = (t < SCAN_NBLK) ? bsum[t] : 0;
    __syncthreads();
    for (int off = 1; off < 256; off <<= 1) {
        int v = (t >= off) ? s[t - off] : 0;
        __syncthreads();
        s[t] += v;
        __syncthreads();
    }
    if (t < SCAN_NBLK) bsum[t] = (t == 0) ? 0 : s[t - 1];  // exclusive
}

__global__ __launch_bounds__(256) void scan3_k(const int* __restrict__ cnt, const int* __restrict__ bsum,
                                               int* __restrict__ row_ptr, int* __restrict__ row_fill) {
    __shared__ int s[256];
    int t = threadIdx.x;
    int i = blockIdx.x * 256 + t;
    int myv = (i < NV) ? cnt[i] : 0;
    s[t] = myv;
    __syncthreads();
    for (int off = 1; off < 256; off <<= 1) {
        int v = (t >= off) ? s[t - off] : 0;
        __syncthreads();
        s[t] += v;
        __syncthreads();
    }
    if (i < NV) {
        int p = bsum[blockIdx.x] + s[t] - myv;  // exclusive
        row_ptr[i] = p;
        row_fill[i] = p;
    }
    if (blockIdx.x == 0 && t == 0) row_ptr[NV] = NE;
}

__global__ void scatter_k(const int* __restrict__ rows, const int* __restrict__ cols,
                          const float* __restrict__ vals,
                          int* __restrict__ row_fill,
                          float* __restrict__ sval, int* __restrict__ scol) {
    int i = blockIdx.x * blockDim.x + threadIdx.x;
    if (i < NE) {
        int r = rows[i];
        int p = atomicAdd(&row_fill[r], 1);
        sval[p] = vals[i];
        scol[p] = cols[i];
    }
}

// x0[v, f*2+b] = inputs[b, v, f]
__global__ void build_x0_k(const float* __restrict__ in, float* __restrict__ x0) {
    int i = blockIdx.x * blockDim.x + threadIdx.x;  // v*64 + f
    if (i < NV * 64) {
        float a = in[i];
        float b = in[(size_t)NV * 64 + i];
        int v = i >> 6, f = i & 63;
        float2* o = (float2*)(x0 + (size_t)v * NC + f * 2);
        *o = make_float2(a, b);
    }
}

// One wave per row, unroll-8 gathers for MLP. mode 0: L x ; mode 1: 2 L x - xprev
__global__ __launch_bounds__(256) void spmm_k(const float* __restrict__ x,
                                              const float* __restrict__ xprev,
                                              const int* __restrict__ row_ptr,
                                              const int* __restrict__ scol,
                                              const float* __restrict__ sval,
                                              float* __restrict__ xout, int mode) {
    int wave = (int)((blockIdx.x * blockDim.x + threadIdx.x) >> 6);
    int lane = threadIdx.x & 63;
    int row = __builtin_amdgcn_readfirstlane(wave);  // force scalar -> s_load for scol/sval
    if (row >= NV) return;
    int beg = row_ptr[row];
    int end = row_ptr[row + 1];
    float ax0 = 0.f, ay0 = 0.f, ax1 = 0.f, ay1 = 0.f;
    int e = beg;
    for (; e + 8 <= end; e += 8) {
        int c0 = scol[e+0], c1 = scol[e+1], c2 = scol[e+2], c3 = scol[e+3];
        int c4 = scol[e+4], c5 = scol[e+5], c6 = scol[e+6], c7 = scol[e+7];
        float w0 = sval[e+0], w1 = sval[e+1], w2 = sval[e+2], w3 = sval[e+3];
        float w4 = sval[e+4], w5 = sval[e+5], w6 = sval[e+6], w7 = sval[e+7];
        float2 g0 = ((const float2*)(x + (size_t)c0 * NC))[lane];
        float2 g1 = ((const float2*)(x + (size_t)c1 * NC))[lane];
        float2 g2 = ((const float2*)(x + (size_t)c2 * NC))[lane];
        float2 g3 = ((const float2*)(x + (size_t)c3 * NC))[lane];
        float2 g4 = ((const float2*)(x + (size_t)c4 * NC))[lane];
        float2 g5 = ((const float2*)(x + (size_t)c5 * NC))[lane];
        float2 g6 = ((const float2*)(x + (size_t)c6 * NC))[lane];
        float2 g7 = ((const float2*)(x + (size_t)c7 * NC))[lane];
        ax0 += w0 * g0.x + w2 * g2.x + w4 * g4.x + w6 * g6.x;
        ay0 += w0 * g0.y + w2 * g2.y + w4 * g4.y + w6 * g6.y;
        ax1 += w1 * g1.x + w3 * g3.x + w5 * g5.x + w7 * g7.x;
        ay1 += w1 * g1.y + w3 * g3.y + w5 * g5.y + w7 * g7.y;
    }
    for (; e < end; ++e) {
        int c = scol[e];
        float w = sval[e];
        float2 g = ((const float2*)(x + (size_t)c * NC))[lane];
        ax0 += w * g.x;
        ay0 += w * g.y;
    }
    float accx = ax0 + ax1, accy = ay0 + ay1;
    float2 res;
    if (mode) {
        float2 pv = ((const float2*)(xprev + (size_t)row * NC))[lane];
        res.x = 2.f * accx - pv.x;
        res.y = 2.f * accy - pv.y;
    } else {
        res.x = accx;
        res.y = accy;
    }
    ((float2*)(xout + (size_t)row * NC))[lane] = res;
}

// Final GEMM: [100000 x 256] @ [256 x 64] + bias. Lane = row (v*2+b), acc[64] in VGPRs,
// weights read with wave-uniform indices -> scalar (SMEM) broadcast loads.
__global__ __launch_bounds__(256) void final_k(const float* __restrict__ x0,
                                               const float* __restrict__ x1,
                                               const float* __restrict__ x2,
                                               const float* __restrict__ x3,
                                               const float* __restrict__ weight,
                                               const float* __restrict__ bias,
                                               float* __restrict__ out) {
    int lane = threadIdx.x & 63;
    int wid = threadIdx.x >> 6;
    int tile = blockIdx.x * 4 + wid;           // 64 rows per tile
    if (tile * 64 >= NROWS) return;            // whole-wave exit
    int r = tile * 64 + lane;
    bool active = (r < NROWS);
    int rc = active ? r : (NROWS - 1);
    int v = rc >> 1;
    int b = rc & 1;

    float acc[64];
    #pragma unroll
    for (int o = 0; o < 64; ++o) acc[o] = bias[o];

    size_t off = (size_t)v * NC;
    #pragma unroll 1
    for (int fp = 0; fp < 32; ++fp) {          // fp covers f = 2fp, 2fp+1
        float4 a0 = *(const float4*)(x0 + off + fp * 4);
        float4 a1 = *(const float4*)(x1 + off + fp * 4);
        float4 a2 = *(const float4*)(x2 + off + fp * 4);
        float4 a3 = *(const float4*)(x3 + off + fp * 4);
        float xe0 = b ? a0.y : a0.x, xo0 = b ? a0.w : a0.z;
        float xe1 = b ? a1.y : a1.x, xo1 = b ? a1.w : a1.z;
        float xe2 = b ? a2.y : a2.x, xo2 = b ? a2.w : a2.z;
        float xe3 = b ? a3.y : a3.x, xo3 = b ? a3.w : a3.z;
        const float* wrow = weight + (size_t)(fp * 8) * 64;  // rows c = 8fp .. 8fp+7
        #pragma unroll
        for (int o = 0; o < 64; ++o) {
            acc[o] += wrow[0 * 64 + o] * xe0;   // c = 8fp+0 (f even, k=0)
            acc[o] += wrow[1 * 64 + o] * xe1;   // k=1
            acc[o] += wrow[2 * 64 + o] * xe2;
            acc[o] += wrow[3 * 64 + o] * xe3;
            acc[o] += wrow[4 * 64 + o] * xo0;   // c = 8fp+4 (f odd, k=0)
            acc[o] += wrow[5 * 64 + o] * xo1;
            acc[o] += wrow[6 * 64 + o] * xo2;
            acc[o] += wrow[7 * 64 + o] * xo3;
        }
    }

    if (active) {
        float* op = out + (size_t)b * (NV * 64) + (size_t)v * 64;
        #pragma unroll
        for (int q = 0; q < 16; ++q) {
            float4 t = make_float4(acc[4 * q + 0], acc[4 * q + 1], acc[4 * q + 2], acc[4 * q + 3]);
            *(float4*)(op + 4 * q) = t;
        }
    }
}

extern "C" void kernel_launch(void* const* d_in, const int* in_sizes, int n_in,
                              void* d_out, int out_size, void* d_ws, size_t ws_size,
                              hipStream_t stream) {
    const float* inputs = (const float*)d_in[0];
    const float* weight = (const float*)d_in[1];
    const float* bias   = (const float*)d_in[2];
    const float* lapv   = (const float*)d_in[3];
    const int*   lrows  = (const int*)d_in[4];
    const int*   lcols  = (const int*)d_in[5];
    float* out = (float*)d_out;

    char* ws = (char*)d_ws;
    size_t o = 0;
    auto alloc = [&](size_t bytes) -> void* {
        void* p = ws + o;
        o += (bytes + 255) & ~(size_t)255;
        return p;
    };
    float* x0 = (float*)alloc((size_t)NV * NC * 4);
    float* x1 = (float*)alloc((size_t)NV * NC * 4);
    float* x2 = (float*)alloc((size_t)NV * NC * 4);
    float* x3 = (float*)alloc((size_t)NV * NC * 4);
    float* sval = (float*)alloc((size_t)NE * 4);
    int* scol = (int*)alloc((size_t)NE * 4);
    int* row_ptr = (int*)alloc((size_t)(NV + 1) * 4);
    int* row_fill = (int*)alloc((size_t)(NV + 1) * 4);
    int* cnt = (int*)alloc((size_t)NV * 4);
    int* bsum = (int*)alloc((size_t)SCAN_NBLK * 4);
    (void)ws_size; (void)in_sizes; (void)n_in; (void)out_size;

    zero_cnt_k<<<(NV + 255) / 256, 256, 0, stream>>>(cnt);
    hist_k<<<(NE + 255) / 256, 256, 0, stream>>>(lrows, cnt);
    scan1_k<<<SCAN_NBLK, 256, 0, stream>>>(cnt, bsum);
    scan2_k<<<1, 256, 0, stream>>>(bsum);
    scan3_k<<<SCAN_NBLK, 256, 0, stream>>>(cnt, bsum, row_ptr, row_fill);
    scatter_k<<<(NE + 255) / 256, 256, 0, stream>>>(lrows, lcols, lapv, row_fill, sval, scol);
    build_x0_k<<<(NV * 64 + 255) / 256, 256, 0, stream>>>(inputs, x0);

    spmm_k<<<(NV + 3) / 4, 256, 0, stream>>>(x0, nullptr, row_ptr, scol, sval, x1, 0);
    spmm_k<<<(NV + 3) / 4, 256, 0, stream>>>(x1, x0, row_ptr, scol, sval, x2, 1);
    spmm_k<<<(NV + 3) / 4, 256, 0, stream>>>(x2, x1, row_ptr, scol, sval, x3, 1);

    final_k<<<(NROWS / 64 + 4) / 4, 256, 0, stream>>>(x0, x1, x2, x3, weight, bias, out);
}

// Round 4
// 304.588 us; speedup vs baseline: 2.5173x; 1.5543x over previous
//
#include <hip/hip_runtime.h>
#include <hip/hip_bf16.h>

// ChebConv K=4. out[b,v,o] = bias[o] + sum_{c<256} xs[c&3][v,(c>>2)*2+b] * Wflat[c*64+o]
// R4: xs stored bf16, layout x[v][b*64+f] (f contiguous). CSR build -> pull spmm
// (bf16 gathers, unroll-8) -> MFMA bf16 epilogue (A direct-from-global, W in LDS).

#define NV 50000
#define NE 800000
#define XROW 128       // elements per x row = 2 batches * 64 features
#define NROWS 100000
#define NTILES 6250    // NROWS / 16
#define SCAN_NBLK 196

using u16 = unsigned short;
using u32 = unsigned int;
typedef __bf16 bf16x8 __attribute__((ext_vector_type(8)));
typedef float f32x4 __attribute__((ext_vector_type(4)));

__device__ __forceinline__ float bflo(u32 g) { return __uint_as_float(g << 16); }
__device__ __forceinline__ float bfhi(u32 g) { return __uint_as_float(g & 0xffff0000u); }
__device__ __forceinline__ u32 pack_bf2(float a, float b) {
    u16 ha = __builtin_bit_cast(u16, (__bf16)a);
    u16 hb = __builtin_bit_cast(u16, (__bf16)b);
    return (u32)ha | ((u32)hb << 16);
}

__global__ void zero_cnt_k(int* __restrict__ cnt) {
    int i = blockIdx.x * blockDim.x + threadIdx.x;
    if (i < NV) cnt[i] = 0;
}

__global__ void hist_k(const int* __restrict__ rows, int* __restrict__ cnt) {
    int i = blockIdx.x * blockDim.x + threadIdx.x;
    if (i < NE) atomicAdd(&cnt[rows[i]], 1);
}

__global__ __launch_bounds__(256) void scan1_k(const int* __restrict__ cnt, int* __restrict__ bsum) {
    __shared__ int s[256];
    int t = threadIdx.x;
    int i = blockIdx.x * 256 + t;
    s[t] = (i < NV) ? cnt[i] : 0;
    __syncthreads();
    for (int off = 128; off > 0; off >>= 1) {
        if (t < off) s[t] += s[t + off];
        __syncthreads();
    }
    if (t == 0) bsum[blockIdx.x] = s[0];
}

__global__ __launch_bounds__(256) void scan2_k(int* __restrict__ bsum) {
    __shared__ int s[256];
    int t = threadIdx.x;
    s[t] = (t < SCAN_NBLK) ? bsum[t] : 0;
    __syncthreads();
    for (int off = 1; off < 256; off <<= 1) {
        int v = (t >= off) ? s[t - off] : 0;
        __syncthreads();
        s[t] += v;
        __syncthreads();
    }
    if (t < SCAN_NBLK) bsum[t] = (t == 0) ? 0 : s[t - 1];
}

__global__ __launch_bounds__(256) void scan3_k(const int* __restrict__ cnt, const int* __restrict__ bsum,
                                               int* __restrict__ row_ptr, int* __restrict__ row_fill) {
    __shared__ int s[256];
    int t = threadIdx.x;
    int i = blockIdx.x * 256 + t;
    int myv = (i < NV) ? cnt[i] : 0;
    s[t] = myv;
    __syncthreads();
    for (int off = 1; off < 256; off <<= 1) {
        int v = (t >= off) ? s[t - off] : 0;
        __syncthreads();
        s[t] += v;
        __syncthreads();
    }
    if (i < NV) {
        int p = bsum[blockIdx.x] + s[t] - myv;
        row_ptr[i] = p;
        row_fill[i] = p;
    }
    if (blockIdx.x == 0 && t == 0) row_ptr[NV] = NE;
}

__global__ void scatter_k(const int* __restrict__ rows, const int* __restrict__ cols,
                          const float* __restrict__ vals,
                          int* __restrict__ row_fill,
                          float* __restrict__ sval, int* __restrict__ scol) {
    int i = blockIdx.x * blockDim.x + threadIdx.x;
    if (i < NE) {
        int r = rows[i];
        int p = atomicAdd(&row_fill[r], 1);
        sval[p] = vals[i];
        scol[p] = cols[i];
    }
}

// x0[v][b*64+f] = bf16(inputs[b,v,f]); thread per uint pair
__global__ void build_x0_k(const float* __restrict__ in, u32* __restrict__ x0u) {
    int i = blockIdx.x * blockDim.x + threadIdx.x;  // uint index: v*64 + p
    if (i < NV * 64) {
        int v = i >> 6, p = i & 63;
        int b = p >> 5;
        int f = (p & 31) * 2;
        const float* src = in + (size_t)b * (NV * 64) + (size_t)v * 64 + f;
        float2 t = *(const float2*)src;
        x0u[i] = pack_bf2(t.x, t.y);
    }
}

// One wave per row. Gathers bf16 rows (uint per lane). mode 0: L x ; 1: 2 L x - xprev
__global__ __launch_bounds__(256) void spmm_k(const u32* __restrict__ x,
                                              const u32* __restrict__ xprev,
                                              const int* __restrict__ row_ptr,
                                              const int* __restrict__ scol,
                                              const float* __restrict__ sval,
                                              u32* __restrict__ xout, int mode) {
    int wave = (int)((blockIdx.x * blockDim.x + threadIdx.x) >> 6);
    int lane = threadIdx.x & 63;
    int row = __builtin_amdgcn_readfirstlane(wave);  // scalar -> s_load for scol/sval
    if (row >= NV) return;
    int beg = row_ptr[row];
    int end = row_ptr[row + 1];
    float ax0 = 0.f, ay0 = 0.f, ax1 = 0.f, ay1 = 0.f;
    int e = beg;
    for (; e + 8 <= end; e += 8) {
        int c0 = scol[e+0], c1 = scol[e+1], c2 = scol[e+2], c3 = scol[e+3];
        int c4 = scol[e+4], c5 = scol[e+5], c6 = scol[e+6], c7 = scol[e+7];
        float w0 = sval[e+0], w1 = sval[e+1], w2 = sval[e+2], w3 = sval[e+3];
        float w4 = sval[e+4], w5 = sval[e+5], w6 = sval[e+6], w7 = sval[e+7];
        u32 g0 = x[(size_t)c0 * 64 + lane];
        u32 g1 = x[(size_t)c1 * 64 + lane];
        u32 g2 = x[(size_t)c2 * 64 + lane];
        u32 g3 = x[(size_t)c3 * 64 + lane];
        u32 g4 = x[(size_t)c4 * 64 + lane];
        u32 g5 = x[(size_t)c5 * 64 + lane];
        u32 g6 = x[(size_t)c6 * 64 + lane];
        u32 g7 = x[(size_t)c7 * 64 + lane];
        ax0 += w0 * bflo(g0) + w2 * bflo(g2) + w4 * bflo(g4) + w6 * bflo(g6);
        ay0 += w0 * bfhi(g0) + w2 * bfhi(g2) + w4 * bfhi(g4) + w6 * bfhi(g6);
        ax1 += w1 * bflo(g1) + w3 * bflo(g3) + w5 * bflo(g5) + w7 * bflo(g7);
        ay1 += w1 * bfhi(g1) + w3 * bfhi(g3) + w5 * bfhi(g5) + w7 * bfhi(g7);
    }
    for (; e < end; ++e) {
        int c = scol[e];
        float w = sval[e];
        u32 g = x[(size_t)c * 64 + lane];
        ax0 += w * bflo(g);
        ay0 += w * bfhi(g);
    }
    float accx = ax0 + ax1, accy = ay0 + ay1;
    if (mode) {
        u32 pv = xprev[(size_t)row * 64 + lane];
        accx = 2.f * accx - bflo(pv);
        accy = 2.f * accy - bfhi(pv);
    }
    xout[(size_t)row * 64 + lane] = pack_bf2(accx, accy);
}

// MFMA epilogue: C[100000 x 64] = X[100000 x 256] @ W'[256 x 64] + bias.
// Column order c' = arr*64 + f (arr = Cheb order); W'[c'][o] = Wflat[(f*4+arr)*64+o].
// Wave computes 16 rows x 64 cols (4 col-tiles of 16x16x32 bf16 MFMA).
__global__ __launch_bounds__(256) void final_k(const u16* __restrict__ x_all,
                                               const float* __restrict__ weight,
                                               const float* __restrict__ bias,
                                               float* __restrict__ out) {
    __shared__ u16 Wt[64 * 264];  // W'^T: Wt[o][c'], stride 264 (2-way bank alias only)
    for (int i = threadIdx.x; i < 256 * 64; i += 256) {
        int c = i >> 6, o = i & 63;
        int cp = ((c & 3) << 6) | (c >> 2);  // c' = (c&3)*64 + (c>>2)
        Wt[o * 264 + cp] = __builtin_bit_cast(u16, (__bf16)weight[i]);
    }
    __syncthreads();

    int lane = threadIdx.x & 63;
    int wid = threadIdx.x >> 6;
    int tile = blockIdx.x * 4 + wid;
    if (tile >= NTILES) return;

    int m = lane & 15;       // A row within tile / C col within col-tile
    int q8 = (lane >> 4) * 8;

    int r = tile * 16 + m;   // row = v*2+b
    int v = r >> 1, b = r & 1;
    const u16* arow = x_all + (size_t)v * XROW + b * 64;

    f32x4 acc0 = {0.f, 0.f, 0.f, 0.f};
    f32x4 acc1 = {0.f, 0.f, 0.f, 0.f};
    f32x4 acc2 = {0.f, 0.f, 0.f, 0.f};
    f32x4 acc3 = {0.f, 0.f, 0.f, 0.f};

    #pragma unroll
    for (int kb = 0; kb < 8; ++kb) {
        int cb = kb * 32 + q8;
        int arr = cb >> 6;
        int f0 = cb & 63;
        bf16x8 a = *(const bf16x8*)(arow + (size_t)arr * (NV * XROW) + f0);
        bf16x8 b0 = *(const bf16x8*)&Wt[(0 * 16 + m) * 264 + kb * 32 + q8];
        bf16x8 b1 = *(const bf16x8*)&Wt[(1 * 16 + m) * 264 + kb * 32 + q8];
        bf16x8 b2 = *(const bf16x8*)&Wt[(2 * 16 + m) * 264 + kb * 32 + q8];
        bf16x8 b3 = *(const bf16x8*)&Wt[(3 * 16 + m) * 264 + kb * 32 + q8];
        acc0 = __builtin_amdgcn_mfma_f32_16x16x32_bf16(a, b0, acc0, 0, 0, 0);
        acc1 = __builtin_amdgcn_mfma_f32_16x16x32_bf16(a, b1, acc1, 0, 0, 0);
        acc2 = __builtin_amdgcn_mfma_f32_16x16x32_bf16(a, b2, acc2, 0, 0, 0);
        acc3 = __builtin_amdgcn_mfma_f32_16x16x32_bf16(a, b3, acc3, 0, 0, 0);
    }

    // C/D: col = lane&15 (o within tile), row = (lane>>4)*4 + reg
    float bv0 = bias[0 * 16 + m];
    float bv1 = bias[1 * 16 + m];
    float bv2 = bias[2 * 16 + m];
    float bv3 = bias[3 * 16 + m];
    int rbase = tile * 16 + (lane >> 4) * 4;
    #pragma unroll
    for (int reg = 0; reg < 4; ++reg) {
        int rr = rbase + reg;
        int vv = rr >> 1, bb = rr & 1;
        float* op = out + (size_t)bb * (NV * 64) + (size_t)vv * 64;
        op[0 * 16 + m] = acc0[reg] + bv0;
        op[1 * 16 + m] = acc1[reg] + bv1;
        op[2 * 16 + m] = acc2[reg] + bv2;
        op[3 * 16 + m] = acc3[reg] + bv3;
    }
}

extern "C" void kernel_launch(void* const* d_in, const int* in_sizes, int n_in,
                              void* d_out, int out_size, void* d_ws, size_t ws_size,
                              hipStream_t stream) {
    const float* inputs = (const float*)d_in[0];
    const float* weight = (const float*)d_in[1];
    const float* bias   = (const float*)d_in[2];
    const float* lapv   = (const float*)d_in[3];
    const int*   lrows  = (const int*)d_in[4];
    const int*   lcols  = (const int*)d_in[5];
    float* out = (float*)d_out;

    char* ws = (char*)d_ws;
    size_t o = 0;
    auto alloc = [&](size_t bytes) -> void* {
        void* p = ws + o;
        o += (bytes + 255) & ~(size_t)255;
        return p;
    };
    u16* x_all = (u16*)alloc((size_t)4 * NV * XROW * 2);  // x0..x3 contiguous, bf16
    float* sval = (float*)alloc((size_t)NE * 4);
    int* scol = (int*)alloc((size_t)NE * 4);
    int* row_ptr = (int*)alloc((size_t)(NV + 1) * 4);
    int* row_fill = (int*)alloc((size_t)(NV + 1) * 4);
    int* cnt = (int*)alloc((size_t)NV * 4);
    int* bsum = (int*)alloc((size_t)SCAN_NBLK * 4);
    (void)ws_size; (void)in_sizes; (void)n_in; (void)out_size;

    u32* x0 = (u32*)(x_all + (size_t)0 * NV * XROW);
    u32* x1 = (u32*)(x_all + (size_t)1 * NV * XROW);
    u32* x2 = (u32*)(x_all + (size_t)2 * NV * XROW);
    u32* x3 = (u32*)(x_all + (size_t)3 * NV * XROW);

    zero_cnt_k<<<(NV + 255) / 256, 256, 0, stream>>>(cnt);
    hist_k<<<(NE + 255) / 256, 256, 0, stream>>>(lrows, cnt);
    scan1_k<<<SCAN_NBLK, 256, 0, stream>>>(cnt, bsum);
    scan2_k<<<1, 256, 0, stream>>>(bsum);
    scan3_k<<<SCAN_NBLK, 256, 0, stream>>>(cnt, bsum, row_ptr, row_fill);
    scatter_k<<<(NE + 255) / 256, 256, 0, stream>>>(lrows, lcols, lapv, row_fill, sval, scol);
    build_x0_k<<<(NV * 64 + 255) / 256, 256, 0, stream>>>(inputs, x0);

    spmm_k<<<(NV + 3) / 4, 256, 0, stream>>>(x0, nullptr, row_ptr, scol, sval, x1, 0);
    spmm_k<<<(NV + 3) / 4, 256, 0, stream>>>(x1, x0, row_ptr, scol, sval, x2, 1);
    spmm_k<<<(NV + 3) / 4, 256, 0, stream>>>(x2, x1, row_ptr, scol, sval, x3, 1);

    final_k<<<(NTILES + 3) / 4, 256, 0, stream>>>(x_all, weight, bias, out);
}

// Round 5
// 292.736 us; speedup vs baseline: 2.6192x; 1.0405x over previous
//
#include <hip/hip_runtime.h>
#include <hip/hip_bf16.h>

// ChebConv K=4. out[b,v,o] = bias[o] + sum_{c<256} xs[c&3][v,(c>>2)*2+b] * Wflat[c*64+o]
// R5: edge records packed (col:u16 | val:f16) -> single 4B scatter store; spmm reads
// packed edge stream via scalar loads. xs bf16 x[v][b*64+f]; MFMA epilogue unchanged.

#define NV 50000
#define NE 800000
#define XROW 128       // elements per x row = 2 batches * 64 features
#define NROWS 100000
#define NTILES 6250    // NROWS / 16
#define SCAN_NBLK 196

using u16 = unsigned short;
using u32 = unsigned int;
typedef __bf16 bf16x8 __attribute__((ext_vector_type(8)));
typedef float f32x4 __attribute__((ext_vector_type(4)));

__device__ __forceinline__ float bflo(u32 g) { return __uint_as_float(g << 16); }
__device__ __forceinline__ float bfhi(u32 g) { return __uint_as_float(g & 0xffff0000u); }
__device__ __forceinline__ u32 pack_bf2(float a, float b) {
    u16 ha = __builtin_bit_cast(u16, (__bf16)a);
    u16 hb = __builtin_bit_cast(u16, (__bf16)b);
    return (u32)ha | ((u32)hb << 16);
}
__device__ __forceinline__ float unpack_f16hi(u32 rec) {
    u16 h = (u16)(rec >> 16);
    return (float)__builtin_bit_cast(_Float16, h);
}

__global__ void zero_cnt_k(int* __restrict__ cnt) {
    int i = blockIdx.x * blockDim.x + threadIdx.x;
    if (i < NV) cnt[i] = 0;
}

__global__ void hist_k(const int* __restrict__ rows, int* __restrict__ cnt) {
    int i = blockIdx.x * blockDim.x + threadIdx.x;
    if (i < NE) atomicAdd(&cnt[rows[i]], 1);
}

__global__ __launch_bounds__(256) void scan1_k(const int* __restrict__ cnt, int* __restrict__ bsum) {
    __shared__ int s[256];
    int t = threadIdx.x;
    int i = blockIdx.x * 256 + t;
    s[t] = (i < NV) ? cnt[i] : 0;
    __syncthreads();
    for (int off = 128; off > 0; off >>= 1) {
        if (t < off) s[t] += s[t + off];
        __syncthreads();
    }
    if (t == 0) bsum[blockIdx.x] = s[0];
}

__global__ __launch_bounds__(256) void scan2_k(int* __restrict__ bsum) {
    __shared__ int s[256];
    int t = threadIdx.x;
    s[t] = (t < SCAN_NBLK) ? bsum[t] : 0;
    __syncthreads();
    for (int off = 1; off < 256; off <<= 1) {
        int v = (t >= off) ? s[t - off] : 0;
        __syncthreads();
        s[t] += v;
        __syncthreads();
    }
    if (t < SCAN_NBLK) bsum[t] = (t == 0) ? 0 : s[t - 1];
}

__global__ __launch_bounds__(256) void scan3_k(const int* __restrict__ cnt, const int* __restrict__ bsum,
                                               int* __restrict__ row_ptr, int* __restrict__ row_fill) {
    __shared__ int s[256];
    int t = threadIdx.x;
    int i = blockIdx.x * 256 + t;
    int myv = (i < NV) ? cnt[i] : 0;
    s[t] = myv;
    __syncthreads();
    for (int off = 1; off < 256; off <<= 1) {
        int v = (t >= off) ? s[t - off] : 0;
        __syncthreads();
        s[t] += v;
        __syncthreads();
    }
    if (i < NV) {
        int p = bsum[blockIdx.x] + s[t] - myv;
        row_ptr[i] = p;
        row_fill[i] = p;
    }
    if (blockIdx.x == 0 && t == 0) row_ptr[NV] = NE;
}

// One 4B store per edge: rec = col | f16(val)<<16
__global__ void scatter_k(const int* __restrict__ rows, const int* __restrict__ cols,
                          const float* __restrict__ vals,
                          int* __restrict__ row_fill,
                          u32* __restrict__ epack) {
    int i = blockIdx.x * blockDim.x + threadIdx.x;
    if (i < NE) {
        int r = rows[i];
        int p = atomicAdd(&row_fill[r], 1);
        u16 hv = __builtin_bit_cast(u16, (_Float16)vals[i]);
        epack[p] = (u32)cols[i] | ((u32)hv << 16);
    }
}

// x0[v][b*64+f] = bf16(inputs[b,v,f]); thread per uint pair
__global__ void build_x0_k(const float* __restrict__ in, u32* __restrict__ x0u) {
    int i = blockIdx.x * blockDim.x + threadIdx.x;  // uint index: v*64 + p
    if (i < NV * 64) {
        int v = i >> 6, p = i & 63;
        int b = p >> 5;
        int f = (p & 31) * 2;
        const float* src = in + (size_t)b * (NV * 64) + (size_t)v * 64 + f;
        float2 t = *(const float2*)src;
        x0u[i] = pack_bf2(t.x, t.y);
    }
}

// One wave per row. Packed edge stream (scalar loads), bf16 row gathers.
// mode 0: L x ; 1: 2 L x - xprev
__global__ __launch_bounds__(256) void spmm_k(const u32* __restrict__ x,
                                              const u32* __restrict__ xprev,
                                              const int* __restrict__ row_ptr,
                                              const u32* __restrict__ epack,
                                              u32* __restrict__ xout, int mode) {
    int wave = (int)((blockIdx.x * blockDim.x + threadIdx.x) >> 6);
    int lane = threadIdx.x & 63;
    int row = __builtin_amdgcn_readfirstlane(wave);  // scalar -> s_load for epack
    if (row >= NV) return;
    int beg = row_ptr[row];
    int end = row_ptr[row + 1];
    float ax0 = 0.f, ay0 = 0.f, ax1 = 0.f, ay1 = 0.f;
    int e = beg;
    for (; e + 8 <= end; e += 8) {
        u32 r0 = epack[e+0], r1 = epack[e+1], r2 = epack[e+2], r3 = epack[e+3];
        u32 r4 = epack[e+4], r5 = epack[e+5], r6 = epack[e+6], r7 = epack[e+7];
        u32 g0 = x[(size_t)(r0 & 0xffff) * 64 + lane];
        u32 g1 = x[(size_t)(r1 & 0xffff) * 64 + lane];
        u32 g2 = x[(size_t)(r2 & 0xffff) * 64 + lane];
        u32 g3 = x[(size_t)(r3 & 0xffff) * 64 + lane];
        u32 g4 = x[(size_t)(r4 & 0xffff) * 64 + lane];
        u32 g5 = x[(size_t)(r5 & 0xffff) * 64 + lane];
        u32 g6 = x[(size_t)(r6 & 0xffff) * 64 + lane];
        u32 g7 = x[(size_t)(r7 & 0xffff) * 64 + lane];
        float w0 = unpack_f16hi(r0), w1 = unpack_f16hi(r1), w2 = unpack_f16hi(r2), w3 = unpack_f16hi(r3);
        float w4 = unpack_f16hi(r4), w5 = unpack_f16hi(r5), w6 = unpack_f16hi(r6), w7 = unpack_f16hi(r7);
        ax0 += w0 * bflo(g0) + w2 * bflo(g2) + w4 * bflo(g4) + w6 * bflo(g6);
        ay0 += w0 * bfhi(g0) + w2 * bfhi(g2) + w4 * bfhi(g4) + w6 * bfhi(g6);
        ax1 += w1 * bflo(g1) + w3 * bflo(g3) + w5 * bflo(g5) + w7 * bflo(g7);
        ay1 += w1 * bfhi(g1) + w3 * bfhi(g3) + w5 * bfhi(g5) + w7 * bfhi(g7);
    }
    for (; e < end; ++e) {
        u32 r0 = epack[e];
        u32 g = x[(size_t)(r0 & 0xffff) * 64 + lane];
        float w = unpack_f16hi(r0);
        ax0 += w * bflo(g);
        ay0 += w * bfhi(g);
    }
    float accx = ax0 + ax1, accy = ay0 + ay1;
    if (mode) {
        u32 pv = xprev[(size_t)row * 64 + lane];
        accx = 2.f * accx - bflo(pv);
        accy = 2.f * accy - bfhi(pv);
    }
    xout[(size_t)row * 64 + lane] = pack_bf2(accx, accy);
}

// MFMA epilogue: C[100000 x 64] = X[100000 x 256] @ W'[256 x 64] + bias.
// Column order c' = arr*64 + f (arr = Cheb order); W'[c'][o] = Wflat[(f*4+arr)*64+o].
__global__ __launch_bounds__(256) void final_k(const u16* __restrict__ x_all,
                                               const float* __restrict__ weight,
                                               const float* __restrict__ bias,
                                               float* __restrict__ out) {
    __shared__ u16 Wt[64 * 264];  // W'^T: Wt[o][c'], stride 264
    for (int i = threadIdx.x; i < 256 * 64; i += 256) {
        int c = i >> 6, o = i & 63;
        int cp = ((c & 3) << 6) | (c >> 2);  // c' = (c&3)*64 + (c>>2)
        Wt[o * 264 + cp] = __builtin_bit_cast(u16, (__bf16)weight[i]);
    }
    __syncthreads();

    int lane = threadIdx.x & 63;
    int wid = threadIdx.x >> 6;
    int tile = blockIdx.x * 4 + wid;
    if (tile >= NTILES) return;

    int m = lane & 15;
    int q8 = (lane >> 4) * 8;

    int r = tile * 16 + m;   // row = v*2+b
    int v = r >> 1, b = r & 1;
    const u16* arow = x_all + (size_t)v * XROW + b * 64;

    f32x4 acc0 = {0.f, 0.f, 0.f, 0.f};
    f32x4 acc1 = {0.f, 0.f, 0.f, 0.f};
    f32x4 acc2 = {0.f, 0.f, 0.f, 0.f};
    f32x4 acc3 = {0.f, 0.f, 0.f, 0.f};

    #pragma unroll
    for (int kb = 0; kb < 8; ++kb) {
        int cb = kb * 32 + q8;
        int arr = cb >> 6;
        int f0 = cb & 63;
        bf16x8 a = *(const bf16x8*)(arow + (size_t)arr * (NV * XROW) + f0);
        bf16x8 b0 = *(const bf16x8*)&Wt[(0 * 16 + m) * 264 + kb * 32 + q8];
        bf16x8 b1 = *(const bf16x8*)&Wt[(1 * 16 + m) * 264 + kb * 32 + q8];
        bf16x8 b2 = *(const bf16x8*)&Wt[(2 * 16 + m) * 264 + kb * 32 + q8];
        bf16x8 b3 = *(const bf16x8*)&Wt[(3 * 16 + m) * 264 + kb * 32 + q8];
        acc0 = __builtin_amdgcn_mfma_f32_16x16x32_bf16(a, b0, acc0, 0, 0, 0);
        acc1 = __builtin_amdgcn_mfma_f32_16x16x32_bf16(a, b1, acc1, 0, 0, 0);
        acc2 = __builtin_amdgcn_mfma_f32_16x16x32_bf16(a, b2, acc2, 0, 0, 0);
        acc3 = __builtin_amdgcn_mfma_f32_16x16x32_bf16(a, b3, acc3, 0, 0, 0);
    }

    float bv0 = bias[0 * 16 + m];
    float bv1 = bias[1 * 16 + m];
    float bv2 = bias[2 * 16 + m];
    float bv3 = bias[3 * 16 + m];
    int rbase = tile * 16 + (lane >> 4) * 4;
    #pragma unroll
    for (int reg = 0; reg < 4; ++reg) {
        int rr = rbase + reg;
        int vv = rr >> 1, bb = rr & 1;
        float* op = out + (size_t)bb * (NV * 64) + (size_t)vv * 64;
        op[0 * 16 + m] = acc0[reg] + bv0;
        op[1 * 16 + m] = acc1[reg] + bv1;
        op[2 * 16 + m] = acc2[reg] + bv2;
        op[3 * 16 + m] = acc3[reg] + bv3;
    }
}

extern "C" void kernel_launch(void* const* d_in, const int* in_sizes, int n_in,
                              void* d_out, int out_size, void* d_ws, size_t ws_size,
                              hipStream_t stream) {
    const float* inputs = (const float*)d_in[0];
    const float* weight = (const float*)d_in[1];
    const float* bias   = (const float*)d_in[2];
    const float* lapv   = (const float*)d_in[3];
    const int*   lrows  = (const int*)d_in[4];
    const int*   lcols  = (const int*)d_in[5];
    float* out = (float*)d_out;

    char* ws = (char*)d_ws;
    size_t o = 0;
    auto alloc = [&](size_t bytes) -> void* {
        void* p = ws + o;
        o += (bytes + 255) & ~(size_t)255;
        return p;
    };
    u16* x_all = (u16*)alloc((size_t)4 * NV * XROW * 2);  // x0..x3 contiguous, bf16
    u32* epack = (u32*)alloc((size_t)NE * 4);
    int* row_ptr = (int*)alloc((size_t)(NV + 1) * 4);
    int* row_fill = (int*)alloc((size_t)(NV + 1) * 4);
    int* cnt = (int*)alloc((size_t)NV * 4);
    int* bsum = (int*)alloc((size_t)SCAN_NBLK * 4);
    (void)ws_size; (void)in_sizes; (void)n_in; (void)out_size;

    u32* x0 = (u32*)(x_all + (size_t)0 * NV * XROW);
    u32* x1 = (u32*)(x_all + (size_t)1 * NV * XROW);
    u32* x2 = (u32*)(x_all + (size_t)2 * NV * XROW);
    u32* x3 = (u32*)(x_all + (size_t)3 * NV * XROW);

    zero_cnt_k<<<(NV + 255) / 256, 256, 0, stream>>>(cnt);
    hist_k<<<(NE + 255) / 256, 256, 0, stream>>>(lrows, cnt);
    scan1_k<<<SCAN_NBLK, 256, 0, stream>>>(cnt, bsum);
    scan2_k<<<1, 256, 0, stream>>>(bsum);
    scan3_k<<<SCAN_NBLK, 256, 0, stream>>>(cnt, bsum, row_ptr, row_fill);
    scatter_k<<<(NE + 255) / 256, 256, 0, stream>>>(lrows, lcols, lapv, row_fill, epack);
    build_x0_k<<<(NV * 64 + 255) / 256, 256, 0, stream>>>(inputs, x0);

    spmm_k<<<(NV + 3) / 4, 256, 0, stream>>>(x0, nullptr, row_ptr, epack, x1, 0);
    spmm_k<<<(NV + 3) / 4, 256, 0, stream>>>(x1, x0, row_ptr, epack, x2, 1);
    spmm_k<<<(NV + 3) / 4, 256, 0, stream>>>(x2, x1, row_ptr, epack, x3, 1);

    final_k<<<(NTILES + 3) / 4, 256, 0, stream>>>(x_all, weight, bias, out);
}